// Round 1
// baseline (1644.849 us; speedup 1.0000x reference)
//
#include <hip/hip_runtime.h>
#include <hip/hip_bf16.h>

// ---------------------------------------------------------------------------
// Swin window attention, MI355X (gfx950), bf16 MFMA pipeline.
//   prep      : fold scale into Wq/bq, bf16 weights, gather rel-pos bias
//   swin_attn : per-window fused QKV GEMM + attention -> attn_out (bf16, ws)
//   proj      : attn_out @ proj_w^T + proj_b -> d_out (fp32)
// ws layout (bytes):
//   0        wqkv   bf16 [1152][384]   (q rows pre-scaled)      884736
//   884736   bqkv   f32  [1152]        (q part pre-scaled)        4608
//   889344   pw     bf16 [384][384]                             294912
//   1184256  biasf  f32  [12][49][49]                           115248
//   1310720  ao     bf16 [4096][49][384]                     154140672
//   total需要 ~148.3 MiB of ws
// ---------------------------------------------------------------------------

#define DIMC 384
#define NHEAD 12
#define HDIM 32
#define NTOK 49
#define NWIN 1024
#define NBW  4096
#define QK_SCALE 0.17677669529663687f   // 32^-0.5

typedef __bf16 bf16x8 __attribute__((ext_vector_type(8)));
typedef __bf16 bf16x4 __attribute__((ext_vector_type(4)));
typedef float  f32x4  __attribute__((ext_vector_type(4)));

#define MFMA16(a,b,c) __builtin_amdgcn_mfma_f32_16x16x32_bf16((a),(b),(c),0,0,0)

// ---------------------------------------------------------------- prep ----
__global__ __launch_bounds__(256) void prep_kernel(
    const float* __restrict__ qkv_w, const float* __restrict__ qkv_b,
    const float* __restrict__ proj_w, const float* __restrict__ rpb,
    const int* __restrict__ rel_idx,
    __bf16* __restrict__ wqkv, float* __restrict__ bqkv,
    __bf16* __restrict__ pw, float* __restrict__ biasf)
{
    long i = (long)blockIdx.x * 256 + threadIdx.x;
    if (i < 442368) {                       // qkv_w -> bf16, scale q rows
        float s = (i < 147456) ? QK_SCALE : 1.0f;
        wqkv[i] = (__bf16)(qkv_w[i] * s);
        return;
    }
    i -= 442368;
    if (i < 1152) {                         // qkv_b (scale q part)
        bqkv[i] = qkv_b[i] * ((i < 384) ? QK_SCALE : 1.0f);
        return;
    }
    i -= 1152;
    if (i < 147456) {                       // proj_w -> bf16 (layout kept)
        pw[i] = (__bf16)proj_w[i];
        return;
    }
    i -= 147456;
    if (i < 28812) {                        // biasf[h][i49*49+j49]
        int h = (int)(i / 2401), ij = (int)(i % 2401);
        biasf[i] = rpb[(long)rel_idx[ij] * NHEAD + h];
    }
}

// ------------------------------------------------- fused QKV + attention ----
// one block = one window; 256 threads = 4 waves; each wave does 3 heads.
// LDS: xs bf16 [64][384] swizzled (48 KB) + per-wave 12 KB scratch:
//   lq [64][32] swz(tok&3), lk [64][32] swz(tok&3), lv [32][64] swz(d&7);
//   lp [64][64] swz(i&7) aliases lq+lk after scores are consumed.
__global__ __launch_bounds__(256, 1) void swin_attn_kernel(
    const float* __restrict__ x, const float* __restrict__ mask,
    const __bf16* __restrict__ wqkv, const float* __restrict__ bqkv,
    const float* __restrict__ biasf, __bf16* __restrict__ ao)
{
    extern __shared__ char smem[];
    const int tid = threadIdx.x;
    const int bw  = blockIdx.x;
    const int wmi = bw & (NWIN - 1);        // mask/window index = bw % 1024

    // ---- stage x -> xs bf16 swizzled; rows 49..63 zero
    {
        const float* xw = x + (long)bw * (NTOK * DIMC);
        for (int it = tid; it < 64 * 48; it += 256) {
            int row = it / 48, s8 = it % 48;           // 8-elem slot
            float4 a = make_float4(0.f, 0.f, 0.f, 0.f);
            float4 b = make_float4(0.f, 0.f, 0.f, 0.f);
            if (row < NTOK) {
                a = *(const float4*)(xw + row * DIMC + s8 * 8);
                b = *(const float4*)(xw + row * DIMC + s8 * 8 + 4);
            }
            bf16x8 hv;
            hv[0] = (__bf16)a.x; hv[1] = (__bf16)a.y;
            hv[2] = (__bf16)a.z; hv[3] = (__bf16)a.w;
            hv[4] = (__bf16)b.x; hv[5] = (__bf16)b.y;
            hv[6] = (__bf16)b.z; hv[7] = (__bf16)b.w;
            int byteoff = row * 768 + ((s8 * 16) ^ ((row & 7) << 4));
            *(bf16x8*)(smem + byteoff) = hv;
        }
    }
    __syncthreads();

    const int lane = tid & 63, wv = tid >> 6;
    const int l15 = lane & 15, lg = lane >> 4;
    char* wbase = smem + 49152 + wv * 12288;

    for (int hh = 0; hh < 3; ++hh) {
        const int h = wv * 3 + hh;

        // ---------------- QKV GEMM: q = x Wq^T ; kT = Wk x^T ; vT = Wv x^T
        f32x4 qacc[4][2] = {};
        f32x4 kacc[2][4] = {};
        f32x4 vacc[2][4] = {};
        const __bf16* wq = wqkv + (long)(h * HDIM) * DIMC;
        const __bf16* wk = wqkv + (long)(384 + h * HDIM) * DIMC;
        const __bf16* wvw = wqkv + (long)(768 + h * HDIM) * DIMC;

        for (int kk = 0; kk < 12; ++kk) {
            const int c0 = kk * 32 + lg * 8;
            bf16x8 xa[4];
#pragma unroll
            for (int m = 0; m < 4; ++m) {
                int row = m * 16 + l15;
                xa[m] = *(const bf16x8*)(smem + row * 768 + ((c0 * 2) ^ ((row & 7) << 4)));
            }
            bf16x8 fq[2], fk[2], fv[2];
#pragma unroll
            for (int n = 0; n < 2; ++n) {
                fq[n] = *(const bf16x8*)(wq + (long)(n * 16 + l15) * DIMC + c0);
                fk[n] = *(const bf16x8*)(wk + (long)(n * 16 + l15) * DIMC + c0);
                fv[n] = *(const bf16x8*)(wvw + (long)(n * 16 + l15) * DIMC + c0);
            }
#pragma unroll
            for (int m = 0; m < 4; ++m)
#pragma unroll
                for (int n = 0; n < 2; ++n)
                    qacc[m][n] = MFMA16(xa[m], fq[n], qacc[m][n]);
#pragma unroll
            for (int m = 0; m < 2; ++m)
#pragma unroll
                for (int n = 0; n < 4; ++n) {
                    kacc[m][n] = MFMA16(fk[m], xa[n], kacc[m][n]);
                    vacc[m][n] = MFMA16(fv[m], xa[n], vacc[m][n]);
                }
        }

        // ---------------- bias add + LDS bounce into MFMA input layouts
        // q tiles: D row = token, col = d  -> lq[token][d]
#pragma unroll
        for (int m = 0; m < 4; ++m) {
#pragma unroll
            for (int n = 0; n < 2; ++n) {
                float qb = bqkv[h * HDIM + n * 16 + l15];
#pragma unroll
                for (int r = 0; r < 4; ++r) {
                    int tok = m * 16 + lg * 4 + r;
                    int d = n * 16 + l15;
                    *(__bf16*)(wbase + tok * 64 + ((d * 2) ^ ((tok & 3) << 4))) =
                        (__bf16)(qacc[m][n][r] + qb);
                }
            }
        }
        // kT tiles: D row = d, col = token -> lk[token][d] (4 consecutive d)
#pragma unroll
        for (int m = 0; m < 2; ++m) {
            const float4 kb = *(const float4*)(bqkv + 384 + h * HDIM + m * 16 + lg * 4);
            float kbr[4] = {kb.x, kb.y, kb.z, kb.w};
#pragma unroll
            for (int n = 0; n < 4; ++n) {
                int tok = n * 16 + l15;
                int d0 = m * 16 + lg * 4;
                bf16x4 pk;
#pragma unroll
                for (int r = 0; r < 4; ++r) pk[r] = (__bf16)(kacc[m][n][r] + kbr[r]);
                *(bf16x4*)(wbase + 4096 + tok * 64 + ((d0 * 2) ^ ((tok & 3) << 4))) = pk;
            }
        }
        // vT tiles: D row = d, col = token -> lv[d][token]
#pragma unroll
        for (int m = 0; m < 2; ++m) {
            const float4 vb = *(const float4*)(bqkv + 768 + h * HDIM + m * 16 + lg * 4);
            float vbr[4] = {vb.x, vb.y, vb.z, vb.w};
#pragma unroll
            for (int n = 0; n < 4; ++n) {
                int tok = n * 16 + l15;
#pragma unroll
                for (int r = 0; r < 4; ++r) {
                    int d = m * 16 + lg * 4 + r;
                    *(__bf16*)(wbase + 8192 + d * 128 + ((tok * 2) ^ ((d & 7) << 4))) =
                        (__bf16)(vacc[m][n][r] + vbr[r]);
                }
            }
        }

        // ---------------- scores = q @ kT  (64x64, K=32)
        f32x4 sacc[4][4] = {};
        {
            bf16x8 qa[4], ka[4];
#pragma unroll
            for (int i = 0; i < 4; ++i) {
                int tr = i * 16 + l15;
                qa[i] = *(const bf16x8*)(wbase + tr * 64 + ((lg * 16) ^ ((tr & 3) << 4)));
                ka[i] = *(const bf16x8*)(wbase + 4096 + tr * 64 + ((lg * 16) ^ ((tr & 3) << 4)));
            }
#pragma unroll
            for (int i = 0; i < 4; ++i)
#pragma unroll
                for (int j = 0; j < 4; ++j)
                    sacc[i][j] = MFMA16(qa[i], ka[j], sacc[i][j]);
        }

        // ---------------- +bias +mask, wave-parallel softmax, p -> lp (bf16)
        const float* bh = biasf + (long)h * 2401;
        const float* mw = mask + (long)wmi * 2401;
        float rinv[4][4];
#pragma unroll
        for (int mi = 0; mi < 4; ++mi) {
#pragma unroll
            for (int r = 0; r < 4; ++r) {
                int i = mi * 16 + lg * 4 + r;
                float mx = -1e30f;
#pragma unroll
                for (int nj = 0; nj < 4; ++nj) {
                    int j = nj * 16 + l15;
                    float s = sacc[mi][nj][r];
                    if (i < NTOK && j < NTOK)
                        s += bh[i * 49 + j] + mw[i * 49 + j];
                    else
                        s = -1e30f;
                    sacc[mi][nj][r] = s;
                    mx = fmaxf(mx, s);
                }
#pragma unroll
                for (int off = 1; off < 16; off <<= 1)
                    mx = fmaxf(mx, __shfl_xor(mx, off, 64));
                float sum = 0.f;
#pragma unroll
                for (int nj = 0; nj < 4; ++nj) {
                    float p = __expf(sacc[mi][nj][r] - mx);
                    sacc[mi][nj][r] = p;
                    sum += p;
                }
#pragma unroll
                for (int off = 1; off < 16; off <<= 1)
                    sum += __shfl_xor(sum, off, 64);
                rinv[mi][r] = 1.0f / sum;
#pragma unroll
                for (int nj = 0; nj < 4; ++nj) {
                    int j = nj * 16 + l15;
                    *(__bf16*)(wbase + i * 128 + ((j * 2) ^ ((i & 7) << 4))) =
                        (__bf16)sacc[mi][nj][r];
                }
            }
        }

        // ---------------- out = p @ v  (64x32, K=64)
        f32x4 oacc[4][2] = {};
#pragma unroll
        for (int kc = 0; kc < 2; ++kc) {
            int j0 = kc * 32 + lg * 8;
            bf16x8 pa[4];
#pragma unroll
            for (int mi = 0; mi < 4; ++mi) {
                int i = mi * 16 + l15;
                pa[mi] = *(const bf16x8*)(wbase + i * 128 + ((j0 * 2) ^ ((i & 7) << 4)));
            }
            bf16x8 vf[2];
#pragma unroll
            for (int nd = 0; nd < 2; ++nd) {
                int d = nd * 16 + l15;
                vf[nd] = *(const bf16x8*)(wbase + 8192 + d * 128 + ((j0 * 2) ^ ((d & 7) << 4)));
            }
#pragma unroll
            for (int mi = 0; mi < 4; ++mi)
#pragma unroll
                for (int nd = 0; nd < 2; ++nd)
                    oacc[mi][nd] = MFMA16(pa[mi], vf[nd], oacc[mi][nd]);
        }

        // ---------------- store attn-out (bf16) [bw][tok][h*32+d]
        __bf16* aow = ao + (long)bw * (NTOK * DIMC) + h * HDIM;
#pragma unroll
        for (int mi = 0; mi < 4; ++mi)
#pragma unroll
            for (int nd = 0; nd < 2; ++nd)
#pragma unroll
                for (int r = 0; r < 4; ++r) {
                    int i = mi * 16 + lg * 4 + r;
                    if (i < NTOK)
                        aow[(long)i * DIMC + nd * 16 + l15] =
                            (__bf16)(oacc[mi][nd][r] * rinv[mi][r]);
                }
    }
}

// ---------------------------------------------------------------- proj ----
// out[200704][384] = ao(bf16) @ pw^T + pb.  1568 blocks x 512 threads.
// 8 waves: 2 (M) x 4 (N); wave tile 64 x 96. Pure global-fed MFMA.
__global__ __launch_bounds__(512, 1) void proj_kernel(
    const __bf16* __restrict__ ao, const __bf16* __restrict__ pw,
    const float* __restrict__ pb, float* __restrict__ out)
{
    const int tid = threadIdx.x, lane = tid & 63, wv = tid >> 6;
    const int wm = wv >> 2, wn = wv & 3;
    const long m0 = (long)blockIdx.x * 128 + wm * 64;
    const int n0 = wn * 96;
    const int l15 = lane & 15, lg = lane >> 4;

    f32x4 acc[4][6] = {};
    for (int kk = 0; kk < 12; ++kk) {
        const int c0 = kk * 32 + lg * 8;
        bf16x8 af[4];
#pragma unroll
        for (int mi = 0; mi < 4; ++mi)
            af[mi] = *(const bf16x8*)(ao + (m0 + mi * 16 + l15) * DIMC + c0);
        bf16x8 bfr[6];
#pragma unroll
        for (int ni = 0; ni < 6; ++ni)
            bfr[ni] = *(const bf16x8*)(pw + (long)(n0 + ni * 16 + l15) * DIMC + c0);
#pragma unroll
        for (int mi = 0; mi < 4; ++mi)
#pragma unroll
            for (int ni = 0; ni < 6; ++ni)
                acc[mi][ni] = MFMA16(af[mi], bfr[ni], acc[mi][ni]);
    }
#pragma unroll
    for (int mi = 0; mi < 4; ++mi)
#pragma unroll
        for (int ni = 0; ni < 6; ++ni) {
            float bias = pb[n0 + ni * 16 + l15];
#pragma unroll
            for (int r = 0; r < 4; ++r)
                out[(m0 + mi * 16 + lg * 4 + r) * DIMC + n0 + ni * 16 + l15] =
                    acc[mi][ni][r] + bias;
        }
}

// ---------------------------------------------------------------------------
extern "C" void kernel_launch(void* const* d_in, const int* in_sizes, int n_in,
                              void* d_out, int out_size, void* d_ws, size_t ws_size,
                              hipStream_t stream)
{
    const float* x      = (const float*)d_in[0];
    const float* mask   = (const float*)d_in[1];
    const float* rpb    = (const float*)d_in[2];
    const float* qkv_w  = (const float*)d_in[3];
    const float* qkv_b  = (const float*)d_in[4];
    const float* proj_w = (const float*)d_in[5];
    const float* proj_b = (const float*)d_in[6];
    const int*   rel_idx = (const int*)d_in[7];
    float* out = (float*)d_out;

    char* ws = (char*)d_ws;
    __bf16* wqkv  = (__bf16*)(ws);
    float*  bqkv  = (float*)(ws + 884736);
    __bf16* pw    = (__bf16*)(ws + 889344);
    float*  biasf = (float*)(ws + 1184256);
    __bf16* ao    = (__bf16*)(ws + 1310720);   // 154140672 bytes

    prep_kernel<<<2422, 256, 0, stream>>>(qkv_w, qkv_b, proj_w, rpb, rel_idx,
                                          wqkv, bqkv, pw, biasf);

    hipFuncSetAttribute((const void*)swin_attn_kernel,
                        hipFuncAttributeMaxDynamicSharedMemorySize, 98304);
    swin_attn_kernel<<<NBW, 256, 98304, stream>>>(x, mask, wqkv, bqkv, biasf, ao);

    proj_kernel<<<1568, 512, 0, stream>>>(ao, pw, proj_b, out);
}